// Round 7
// baseline (632.755 us; speedup 1.0000x reference)
//
#include <hip/hip_runtime.h>

// ---------------------------------------------------------------------------
// ConvLSTMNet round 14:
//  - lstm: exact R10 (best measured 317 us, 80 VGPR, 4-wave blocks).
//  - FC: LDS-free fc_gemm. A is wave-uniform (wave wv owns rows 16wv..+15),
//    so A reads compile to s_load on the scalar pipe (row0 forced uniform
//    via readfirstlane): no staging, no ds_read, and ZERO __syncthreads.
//    Body = {s_load A row-slices, 16 coalesced W loads, 256 FMA} per group;
//    8 blocks/CU (no LDS) doubles latency-hiding TLP. Split counts raised
//    (fc2 44x160 exact, fc3 107x32, fc4 63x16, fc5 32x16). k-order per
//    (m,n) unchanged -> absmax ~= R13. Atomic split-K + fc_init kept.
// ---------------------------------------------------------------------------

#define T_STEPS 256
#define PIX 55
#define MT 16          // sequences per tile (MFMA N-dim)
#define TILES 110      // 1760 / 16
#define LOG2E 1.4426950408889634f
#define FC_GRP 16      // k-depth per load/FMA group

typedef float f32x4 __attribute__((ext_vector_type(4)));
typedef __bf16 bf16x8 __attribute__((ext_vector_type(8)));
typedef __bf16 bf16x4 __attribute__((ext_vector_type(4)));

__global__ __launch_bounds__(256) void lstm_kernel(
    const float* __restrict__ x1, const float* __restrict__ x2,
    const float* __restrict__ wx1, const float* __restrict__ wh1,
    const float* __restrict__ bx1, const float* __restrict__ bh1,
    const float* __restrict__ wx2, const float* __restrict__ wh2,
    const float* __restrict__ bx2, const float* __restrict__ bh2,
    float* __restrict__ feat)   // [64][7040]: row sub*32+b, col (cell*64+u)*55+p
{
    int bid  = blockIdx.x;            // 0..439
    int tile = bid % TILES;
    int cc   = bid / TILES;           // 0..3
    int sub  = cc >> 1, cell = cc & 1;
    const float* x  = sub  ? x2  : x1;
    const float* wx = cell ? wx2 : wx1;
    const float* wh = cell ? wh2 : wh1;
    const float* bx = cell ? bx2 : bx1;
    const float* bh = cell ? bh2 : bh1;

    int tid  = threadIdx.x;
    int w    = tid >> 6;              // wave id = unit subtile (units 16w..16w+15)
    int l    = tid & 63;
    int quad = l >> 4;
    int c16  = l & 15;

    __shared__ float xl[MT * 514];                        // [seq][t*2+c], pad 514
    __shared__ __align__(16) __bf16 hb[2][2][MT][72];     // [buf][hi/lo][seq][u pad72]

    // ---- stage x for this block's 16 sequences (all 256 steps) ----
    {
        int seq0 = tile * MT;
        for (int i = 0; i < 32; ++i) {
            int idx = tid + 256 * i;          // m*512 + t*2 + c
            int m = idx >> 9;
            int tc = idx & 511;
            int t = tc >> 1, c = tc & 1;
            int seq = seq0 + m;
            int b = seq / PIX, p = seq % PIX;
            xl[m * 514 + tc] = x[((b * T_STEPS + t) * 2 + c) * PIX + p];
        }
    }
    // ---- zero h buffers ----
    {
        __bf16* hz = &hb[0][0][0][0];
        for (int i = tid; i < 2 * 2 * MT * 72; i += 256) hz[i] = (__bf16)0.0f;
    }

    // ---- W as A-operand fragments (hi+lo), per gate & K-slab ----
    bf16x8 Whi[4][2], Wlo[4][2];
    float btot[4][4], wxa[4][4], wxb[4][4];
#pragma unroll
    for (int g = 0; g < 4; ++g) {
        int col = 64 * g + 16 * w + c16;
#pragma unroll
        for (int r = 0; r < 4; ++r) {
            int u = 64 * g + 16 * w + 4 * quad + r;   // this thread's C-row units
            btot[g][r] = bx[u] + bh[u];
            wxa[g][r]  = wx[u];
            wxb[g][r]  = wx[256 + u];
        }
#pragma unroll
        for (int q = 0; q < 2; ++q) {
#pragma unroll
            for (int j = 0; j < 8; ++j) {
                int k = 32 * q + 8 * quad + j;
                float wv = wh[k * 256 + col];
                __bf16 hi = (__bf16)wv;
                Whi[g][q][j] = hi;
                Wlo[g][q][j] = (__bf16)(wv - (float)hi);
            }
        }
    }

    float cst[4]  = {0.f, 0.f, 0.f, 0.f};
    float hfin[4] = {0.f, 0.f, 0.f, 0.f};

    // xv for step 0 (xl is read-only after staging; prefetched pre-barrier
    // for every later step)
    __syncthreads();
    float2 xv = *(const float2*)&xl[c16 * 514 + (cell ? (T_STEPS - 1) : 0) * 2];

#pragma unroll 2
    for (int t = 0; t < T_STEPS; ++t) {
        int rb = t & 1, wb = rb ^ 1;

        bf16x8 Bh[2], Bl[2];
#pragma unroll
        for (int q = 0; q < 2; ++q) {
            Bh[q] = *(const bf16x8*)&hb[rb][0][c16][32 * q + 8 * quad];
            Bl[q] = *(const bf16x8*)&hb[rb][1][c16][32 * q + 8 * quad];
        }

        f32x4 acc[4];
#pragma unroll
        for (int g = 0; g < 4; ++g) {
#pragma unroll
            for (int r = 0; r < 4; ++r)
                acc[g][r] = fmaf(xv.y, wxb[g][r], fmaf(xv.x, wxa[g][r], btot[g][r]));
        }
        // product-major: 6 rounds x 4 gates -> 4-way dependent-chain ILP.
#pragma unroll
        for (int g = 0; g < 4; ++g)
            acc[g] = __builtin_amdgcn_mfma_f32_16x16x32_bf16(Whi[g][0], Bh[0], acc[g], 0, 0, 0);
#pragma unroll
        for (int g = 0; g < 4; ++g)
            acc[g] = __builtin_amdgcn_mfma_f32_16x16x32_bf16(Whi[g][1], Bh[1], acc[g], 0, 0, 0);
#pragma unroll
        for (int g = 0; g < 4; ++g)
            acc[g] = __builtin_amdgcn_mfma_f32_16x16x32_bf16(Wlo[g][0], Bh[0], acc[g], 0, 0, 0);
#pragma unroll
        for (int g = 0; g < 4; ++g)
            acc[g] = __builtin_amdgcn_mfma_f32_16x16x32_bf16(Wlo[g][1], Bh[1], acc[g], 0, 0, 0);
#pragma unroll
        for (int g = 0; g < 4; ++g)
            acc[g] = __builtin_amdgcn_mfma_f32_16x16x32_bf16(Whi[g][0], Bl[0], acc[g], 0, 0, 0);
#pragma unroll
        for (int g = 0; g < 4; ++g)
            acc[g] = __builtin_amdgcn_mfma_f32_16x16x32_bf16(Whi[g][1], Bl[1], acc[g], 0, 0, 0);

        // exp phase: 16 independent transcendentals, streamed
        float ei[4], ef[4], eo[4], eg[4];
#pragma unroll
        for (int r = 0; r < 4; ++r) {
            ei[r] = __builtin_amdgcn_exp2f(-LOG2E * acc[0][r]);
            ef[r] = __builtin_amdgcn_exp2f(-LOG2E * acc[1][r]);
            eo[r] = __builtin_amdgcn_exp2f(-LOG2E * acc[2][r]);
            eg[r] = __builtin_amdgcn_exp2f(-2.0f * LOG2E * acc[3][r]);
        }

        bf16x4 ph, pl;
#pragma unroll
        for (int r = 0; r < 4; ++r) {
            float sf  = __builtin_amdgcn_rcpf(1.0f + ef[r]);
            float itg = (1.0f - eg[r]) * __builtin_amdgcn_rcpf((1.0f + ei[r]) * (1.0f + eg[r]));
            float c   = fmaf(sf, cst[r], itg);
            cst[r] = c;
            float ec = __builtin_amdgcn_exp2f(-2.0f * LOG2E * c);
            float h  = (1.0f - ec) * __builtin_amdgcn_rcpf((1.0f + eo[r]) * (1.0f + ec));
            hfin[r] = h;
            __bf16 hi = (__bf16)h;
            ph[r] = hi;
            pl[r] = (__bf16)(h - (float)hi);
        }
        *(bf16x4*)&hb[wb][0][c16][16 * w + 4 * quad] = ph;
        *(bf16x4*)&hb[wb][1][c16][16 * w + 4 * quad] = pl;

        // prefetch next step's x contribution BEFORE the barrier (xl is
        // read-only; &255 keeps the dead last-iteration index in-bounds)
        {
            int txn = (cell ? (T_STEPS - 2 - t) : (t + 1)) & 255;
            xv = *(const float2*)&xl[c16 * 514 + txn * 2];
        }
        __syncthreads();
    }

    {
        int seq = tile * MT + c16;
        int b = seq / PIX, p = seq % PIX;
#pragma unroll
        for (int r = 0; r < 4; ++r) {
            int u = 16 * w + 4 * quad + r;
            feat[(size_t)(sub * 32 + b) * 7040 + (cell * 64 + u) * PIX + p] = hfin[r];
        }
    }
}

// ---------------------------------------------------------------------------
// fc_init: pre-fill all four FC outputs with their bias rows (replaces the
// four fc_reduce launches; fc_gemm then accumulates atomically).
// Layout: t1[64][3400], t2[64][1000], t3[64][500], o[64][50].
// ---------------------------------------------------------------------------
__global__ __launch_bounds__(256) void fc_init(
    const float* __restrict__ b2, const float* __restrict__ b3,
    const float* __restrict__ b4, const float* __restrict__ b5,
    float* __restrict__ t1, float* __restrict__ t2,
    float* __restrict__ t3, float* __restrict__ o)
{
    int i = blockIdx.x * 256 + threadIdx.x;
    const int n1 = 64 * 3400, n2 = 64 * 1000, n3 = 64 * 500, n4 = 64 * 50;
    if (i < n1) { t1[i] = b2[i % 3400]; return; }
    i -= n1;
    if (i < n2) { t2[i] = b3[i % 1000]; return; }
    i -= n2;
    if (i < n3) { t3[i] = b4[i % 500]; return; }
    i -= n3;
    if (i < n4) { o[i] = b5[i % 50]; }
}

// ---------------------------------------------------------------------------
// FC v6 (LDS-free, scalar-A): out[64][N] += A[64][kchunk] @ W[kchunk][N].
// Block = 64 m x 64 n; lane owns ONE n (acc[16]). Wave wv owns rows
// 16wv..16wv+15: A addresses are wave-uniform (row0 via readfirstlane) so
// A reads are s_load on the scalar pipe -- no LDS, no staging, no barriers.
// W: 16-deep coalesced groups (256 B/wave/instr). 8 blocks/CU occupancy.
// Accumulation into bias-pre-initialized out via native f32 atomics.
// ---------------------------------------------------------------------------
__global__ __launch_bounds__(256) void fc_gemm(const float* __restrict__ A,
                                               const float* __restrict__ W,
                                               float* __restrict__ out,
                                               int K, int N, int kchunk) {
    int tid  = threadIdx.x;
    int l    = tid & 63;
    int row0 = __builtin_amdgcn_readfirstlane((tid >> 6) * 16);  // wave-uniform
    int k0   = blockIdx.y * kchunk;
    int kend = min(K, k0 + kchunk);

    int n  = blockIdx.x * 64 + l;
    int ne = min(n, N - 1);                // clamped load index (stores guarded)

    const float* ar = A + (size_t)row0 * K;   // uniform base -> s_load path
    const float* wp = W + ne;

    float acc[16];
#pragma unroll
    for (int i = 0; i < 16; ++i) acc[i] = 0.0f;

    int ks = k0;
    for (; ks + FC_GRP <= kend; ks += FC_GRP) {
        float wbuf[FC_GRP];
#pragma unroll
        for (int j = 0; j < FC_GRP; ++j)
            wbuf[j] = wp[(size_t)(ks + j) * N];     // 16 independent, coalesced
#pragma unroll
        for (int j = 0; j < FC_GRP; ++j) {
#pragma unroll
            for (int m = 0; m < 16; ++m)
                acc[m] = fmaf(ar[(size_t)m * K + ks + j], wbuf[j], acc[m]);
        }
    }
    for (; ks < kend; ++ks) {              // tail (<16 k)
        float wvv = wp[(size_t)ks * N];
#pragma unroll
        for (int m = 0; m < 16; ++m)
            acc[m] = fmaf(ar[(size_t)m * K + ks], wvv, acc[m]);
    }

    if (n < N) {
        float* pr = out + n;
#pragma unroll
        for (int i = 0; i < 16; ++i)
            unsafeAtomicAdd(&pr[(size_t)(row0 + i) * N], acc[i]);
    }
}

extern "C" void kernel_launch(void* const* d_in, const int* in_sizes, int n_in,
                              void* d_out, int out_size, void* d_ws, size_t ws_size,
                              hipStream_t stream) {
    const float* x1  = (const float*)d_in[0];
    const float* x2  = (const float*)d_in[1];
    const float* wx1 = (const float*)d_in[2];
    const float* wh1 = (const float*)d_in[3];
    const float* bx1 = (const float*)d_in[4];
    const float* bh1 = (const float*)d_in[5];
    const float* wx2 = (const float*)d_in[6];
    const float* wh2 = (const float*)d_in[7];
    const float* bx2 = (const float*)d_in[8];
    const float* bh2 = (const float*)d_in[9];
    const float* fw2 = (const float*)d_in[10];
    const float* fb2 = (const float*)d_in[11];
    const float* fw3 = (const float*)d_in[12];
    const float* fb3 = (const float*)d_in[13];
    const float* fw4 = (const float*)d_in[14];
    const float* fb4 = (const float*)d_in[15];
    const float* fw5 = (const float*)d_in[16];
    const float* fb5 = (const float*)d_in[17];

    char* ws = (char*)d_ws;
    float* feat = (float*)ws;                                   // [64][7040]
    float* t1   = feat + (size_t)64 * 7040;                     // [64][3400]
    float* t2   = t1   + (size_t)64 * 3400;                     // [64][1000]
    float* t3   = t2   + (size_t)64 * 1000;                     // [64][500]
    float* o    = (float*)d_out;                                // [64][50]

    // bias pre-fill for all four FC outputs (316800 elems)
    fc_init<<<dim3(1238), dim3(256), 0, stream>>>(fb2, fb3, fb4, fb5, t1, t2, t3, o);

    lstm_kernel<<<dim3(440), dim3(256), 0, stream>>>(
        x1, x2, wx1, wh1, bx1, bh1, wx2, wh2, bx2, bh2, feat);

    // atomic split-K GEMMs (out pre-filled with bias); no LDS -> deep splits
    fc_gemm<<<dim3(54, 44), dim3(256), 0, stream>>>(feat, fw2, t1, 7040, 3400, 160);
    fc_gemm<<<dim3(16, 107), dim3(256), 0, stream>>>(t1, fw3, t2, 3400, 1000, 32);
    fc_gemm<<<dim3(8, 63), dim3(256), 0, stream>>>(t2, fw4, t3, 1000, 500, 16);
    fc_gemm<<<dim3(1, 32), dim3(256), 0, stream>>>(t3, fw5, o, 500, 50, 16);
}

// Round 8
// 573.585 us; speedup vs baseline: 1.1032x; 1.1032x over previous
//
#include <hip/hip_runtime.h>

// ---------------------------------------------------------------------------
// ConvLSTMNet round 15:
//  - lstm: MT=32 wide-N blocks. Each wave owns 16 units x 32 seqs (two 16-seq
//    MFMA column-tiles). W fragments are SHARED across both halves (regs stay
//    64; acc/B/state double -> ~200 VGPR, no spill at 1 wave/SIMD). 55x4 =
//    220 blocks <= 256 CUs and LDS 84KB -> exactly 1 block/CU, 1 wave/SIMD:
//    kills the 2-waves-per-SIMD barrier lock-step that set the old wall.
//    8-way MFMA ILP (4 gates x 2 halves). Same math order -> same absmax.
//  - FC: exact R10 revert (233 us proven; scalar-A/no-LDS variant regressed).
// ---------------------------------------------------------------------------

#define T_STEPS 256
#define PIX 55
#define MT 32          // sequences per tile (2 x MFMA N-dim)
#define TILES 55       // 1760 / 32
#define LOG2E 1.4426950408889634f
#define FC_SUB 128     // kc per LDS stage
#define FC_GRP 16      // W pipeline depth

typedef float f32x4 __attribute__((ext_vector_type(4)));
typedef __bf16 bf16x8 __attribute__((ext_vector_type(8)));
typedef __bf16 bf16x4 __attribute__((ext_vector_type(4)));

__global__ __launch_bounds__(256, 1) void lstm_kernel(
    const float* __restrict__ x1, const float* __restrict__ x2,
    const float* __restrict__ wx1, const float* __restrict__ wh1,
    const float* __restrict__ bx1, const float* __restrict__ bh1,
    const float* __restrict__ wx2, const float* __restrict__ wh2,
    const float* __restrict__ bx2, const float* __restrict__ bh2,
    float* __restrict__ feat)   // [64][7040]: row sub*32+b, col (cell*64+u)*55+p
{
    int bid  = blockIdx.x;            // 0..219
    int tile = bid % TILES;
    int cc   = bid / TILES;           // 0..3
    int sub  = cc >> 1, cell = cc & 1;
    const float* x  = sub  ? x2  : x1;
    const float* wx = cell ? wx2 : wx1;
    const float* wh = cell ? wh2 : wh1;
    const float* bx = cell ? bx2 : bx1;
    const float* bh = cell ? bh2 : bh1;

    int tid  = threadIdx.x;
    int w    = tid >> 6;              // wave id = unit subtile (units 16w..16w+15)
    int l    = tid & 63;
    int quad = l >> 4;
    int c16  = l & 15;

    __shared__ float xl[MT * 514];                        // [seq][t*2+c], pad 514 (65.8 KB)
    __shared__ __align__(16) __bf16 hb[2][2][MT][72];     // [buf][hi/lo][seq][u pad72] (18.4 KB)

    // ---- stage x for this block's 32 sequences (all 256 steps) ----
    {
        int seq0 = tile * MT;
        for (int i = 0; i < 64; ++i) {
            int idx = tid + 256 * i;          // m*512 + t*2 + c
            int m = idx >> 9;                 // 0..31
            int tc = idx & 511;
            int t = tc >> 1, c = tc & 1;
            int seq = seq0 + m;
            int b = seq / PIX, p = seq % PIX;
            xl[m * 514 + tc] = x[((b * T_STEPS + t) * 2 + c) * PIX + p];
        }
    }
    // ---- zero h buffers ----
    {
        __bf16* hz = &hb[0][0][0][0];
        for (int i = tid; i < 2 * 2 * MT * 72; i += 256) hz[i] = (__bf16)0.0f;
    }

    // ---- W as A-operand fragments (hi+lo), per gate & K-slab (SHARED by halves) ----
    bf16x8 Whi[4][2], Wlo[4][2];
    float btot[4][4], wxa[4][4], wxb[4][4];
#pragma unroll
    for (int g = 0; g < 4; ++g) {
        int col = 64 * g + 16 * w + c16;
#pragma unroll
        for (int r = 0; r < 4; ++r) {
            int u = 64 * g + 16 * w + 4 * quad + r;   // this thread's C-row units
            btot[g][r] = bx[u] + bh[u];
            wxa[g][r]  = wx[u];
            wxb[g][r]  = wx[256 + u];
        }
#pragma unroll
        for (int q = 0; q < 2; ++q) {
#pragma unroll
            for (int j = 0; j < 8; ++j) {
                int k = 32 * q + 8 * quad + j;
                float wv = wh[k * 256 + col];
                __bf16 hi = (__bf16)wv;
                Whi[g][q][j] = hi;
                Wlo[g][q][j] = (__bf16)(wv - (float)hi);
            }
        }
    }

    float cst[2][4]  = {{0.f,0.f,0.f,0.f},{0.f,0.f,0.f,0.f}};
    float hfin[2][4] = {{0.f,0.f,0.f,0.f},{0.f,0.f,0.f,0.f}};

    __syncthreads();
    // xv for step 0, both halves (xl read-only; prefetched pre-barrier later)
    float2 xv[2];
    {
        int tx0 = cell ? (T_STEPS - 1) : 0;
        xv[0] = *(const float2*)&xl[(c16     ) * 514 + tx0 * 2];
        xv[1] = *(const float2*)&xl[(c16 + 16) * 514 + tx0 * 2];
    }

#pragma unroll 2
    for (int t = 0; t < T_STEPS; ++t) {
        int rb = t & 1, wb = rb ^ 1;

        bf16x8 Bh[2][2], Bl[2][2];            // [half][kslab]
#pragma unroll
        for (int nh = 0; nh < 2; ++nh)
#pragma unroll
            for (int q = 0; q < 2; ++q) {
                Bh[nh][q] = *(const bf16x8*)&hb[rb][0][c16 + 16 * nh][32 * q + 8 * quad];
                Bl[nh][q] = *(const bf16x8*)&hb[rb][1][c16 + 16 * nh][32 * q + 8 * quad];
            }

        f32x4 acc[4][2];                      // [gate][half]
#pragma unroll
        for (int g = 0; g < 4; ++g)
#pragma unroll
            for (int nh = 0; nh < 2; ++nh)
#pragma unroll
                for (int r = 0; r < 4; ++r)
                    acc[g][nh][r] = fmaf(xv[nh].y, wxb[g][r],
                                         fmaf(xv[nh].x, wxa[g][r], btot[g][r]));

        // product-major: 6 rounds x 8 tiles (4 gates x 2 halves) -> 8-way ILP.
        // Per-acc accumulation order identical to the MT=16 kernel.
#pragma unroll
        for (int g = 0; g < 4; ++g)
#pragma unroll
            for (int nh = 0; nh < 2; ++nh)
                acc[g][nh] = __builtin_amdgcn_mfma_f32_16x16x32_bf16(Whi[g][0], Bh[nh][0], acc[g][nh], 0, 0, 0);
#pragma unroll
        for (int g = 0; g < 4; ++g)
#pragma unroll
            for (int nh = 0; nh < 2; ++nh)
                acc[g][nh] = __builtin_amdgcn_mfma_f32_16x16x32_bf16(Whi[g][1], Bh[nh][1], acc[g][nh], 0, 0, 0);
#pragma unroll
        for (int g = 0; g < 4; ++g)
#pragma unroll
            for (int nh = 0; nh < 2; ++nh)
                acc[g][nh] = __builtin_amdgcn_mfma_f32_16x16x32_bf16(Wlo[g][0], Bh[nh][0], acc[g][nh], 0, 0, 0);
#pragma unroll
        for (int g = 0; g < 4; ++g)
#pragma unroll
            for (int nh = 0; nh < 2; ++nh)
                acc[g][nh] = __builtin_amdgcn_mfma_f32_16x16x32_bf16(Wlo[g][1], Bh[nh][1], acc[g][nh], 0, 0, 0);
#pragma unroll
        for (int g = 0; g < 4; ++g)
#pragma unroll
            for (int nh = 0; nh < 2; ++nh)
                acc[g][nh] = __builtin_amdgcn_mfma_f32_16x16x32_bf16(Whi[g][0], Bl[nh][0], acc[g][nh], 0, 0, 0);
#pragma unroll
        for (int g = 0; g < 4; ++g)
#pragma unroll
            for (int nh = 0; nh < 2; ++nh)
                acc[g][nh] = __builtin_amdgcn_mfma_f32_16x16x32_bf16(Whi[g][1], Bl[nh][1], acc[g][nh], 0, 0, 0);

        // per half: exp phase (16 independent transcendentals) then combine
#pragma unroll
        for (int nh = 0; nh < 2; ++nh) {
            float ei[4], ef[4], eo[4], eg[4];
#pragma unroll
            for (int r = 0; r < 4; ++r) {
                ei[r] = __builtin_amdgcn_exp2f(-LOG2E * acc[0][nh][r]);
                ef[r] = __builtin_amdgcn_exp2f(-LOG2E * acc[1][nh][r]);
                eo[r] = __builtin_amdgcn_exp2f(-LOG2E * acc[2][nh][r]);
                eg[r] = __builtin_amdgcn_exp2f(-2.0f * LOG2E * acc[3][nh][r]);
            }
            bf16x4 ph, pl;
#pragma unroll
            for (int r = 0; r < 4; ++r) {
                float sf  = __builtin_amdgcn_rcpf(1.0f + ef[r]);
                float itg = (1.0f - eg[r]) * __builtin_amdgcn_rcpf((1.0f + ei[r]) * (1.0f + eg[r]));
                float c   = fmaf(sf, cst[nh][r], itg);
                cst[nh][r] = c;
                float ec = __builtin_amdgcn_exp2f(-2.0f * LOG2E * c);
                float h  = (1.0f - ec) * __builtin_amdgcn_rcpf((1.0f + eo[r]) * (1.0f + ec));
                hfin[nh][r] = h;
                __bf16 hi = (__bf16)h;
                ph[r] = hi;
                pl[r] = (__bf16)(h - (float)hi);
            }
            *(bf16x4*)&hb[wb][0][c16 + 16 * nh][16 * w + 4 * quad] = ph;
            *(bf16x4*)&hb[wb][1][c16 + 16 * nh][16 * w + 4 * quad] = pl;
        }

        // prefetch next step's x contributions BEFORE the barrier
        {
            int txn = (cell ? (T_STEPS - 2 - t) : (t + 1)) & 255;
            xv[0] = *(const float2*)&xl[(c16     ) * 514 + txn * 2];
            xv[1] = *(const float2*)&xl[(c16 + 16) * 514 + txn * 2];
        }
        __syncthreads();
    }

    {
#pragma unroll
        for (int nh = 0; nh < 2; ++nh) {
            int seq = tile * MT + c16 + 16 * nh;
            int b = seq / PIX, p = seq % PIX;
#pragma unroll
            for (int r = 0; r < 4; ++r) {
                int u = 16 * w + 4 * quad + r;
                feat[(size_t)(sub * 32 + b) * 7040 + (cell * 64 + u) * PIX + p] = hfin[nh][r];
            }
        }
    }
}

// ---------------------------------------------------------------------------
// fc_init: pre-fill all four FC outputs with their bias rows (replaces the
// four fc_reduce launches; fc_gemm then accumulates atomically).
// Layout: t1[64][3400], t2[64][1000], t3[64][500], o[64][50].
// ---------------------------------------------------------------------------
__global__ __launch_bounds__(256) void fc_init(
    const float* __restrict__ b2, const float* __restrict__ b3,
    const float* __restrict__ b4, const float* __restrict__ b5,
    float* __restrict__ t1, float* __restrict__ t2,
    float* __restrict__ t3, float* __restrict__ o)
{
    int i = blockIdx.x * 256 + threadIdx.x;
    const int n1 = 64 * 3400, n2 = 64 * 1000, n3 = 64 * 500, n4 = 64 * 50;
    if (i < n1) { t1[i] = b2[i % 3400]; return; }
    i -= n1;
    if (i < n2) { t2[i] = b3[i % 1000]; return; }
    i -= n2;
    if (i < n3) { t3[i] = b4[i % 500]; return; }
    i -= n3;
    if (i < n4) { o[i] = b5[i % 50]; }
}

// ---------------------------------------------------------------------------
// FC slim v3 (R10, proven 233 us): out[64][N] += A[64][kchunk] @ W[kchunk][N].
// Block = 64 m x 64 n. Lane owns ONE n (acc[16] = 16 VGPR). Wave w -> rows
// 16w..16w+15 (broadcast b128 A reads). kcur==128 path: 8x16 static groups.
// Accumulation into bias-pre-initialized out via native f32 atomics.
// ---------------------------------------------------------------------------
__global__ __launch_bounds__(256) void fc_gemm(const float* __restrict__ A,
                                               const float* __restrict__ W,
                                               float* __restrict__ out,
                                               int K, int N, int kchunk) {
    __shared__ __align__(16) float al[FC_SUB * 68];   // [kc][m pad68]
    int tid = threadIdx.x;
    int l   = tid & 63;
    int wv  = tid >> 6;
    int k0   = blockIdx.y * kchunk;
    int kend = min(K, k0 + kchunk);

    int n  = blockIdx.x * 64 + l;
    int ne = min(n, N - 1);                // clamped load index (stores guarded)

    float acc[16];
#pragma unroll
    for (int i = 0; i < 16; ++i) acc[i] = 0.0f;

    for (int ks = k0; ks < kend; ks += FC_SUB) {
        int kcur = min(FC_SUB, kend - ks);
        __syncthreads();                   // protect al reuse
        // ---- stage A[0:64][ks:ks+kcur]: 32 independent coalesced loads ----
        if (kcur == FC_SUB) {
#pragma unroll
            for (int i = 0; i < 32; ++i) {
                int idx = tid + 256 * i;       // m = idx>>7, kc = idx&127
                int m = idx >> 7, kc = idx & 127;
                al[kc * 68 + m] = A[(size_t)m * K + ks + kc];
            }
        } else {
#pragma unroll
            for (int i = 0; i < 32; ++i) {
                int idx = tid + 256 * i;
                int m = idx >> 7, kc = idx & 127;
                if (kc < kcur) al[kc * 68 + m] = A[(size_t)m * K + ks + kc];
            }
        }
        __syncthreads();

        const float* wr = W + (size_t)ks * N + ne;
        if (kcur == FC_SUB) {
            // hot path: 8 static groups of 16, fully unrolled
#pragma unroll
            for (int g8 = 0; g8 < FC_SUB / FC_GRP; ++g8) {
                float wbuf[FC_GRP];
#pragma unroll
                for (int j = 0; j < FC_GRP; ++j)
                    wbuf[j] = wr[(size_t)(g8 * FC_GRP + j) * N];
#pragma unroll
                for (int j = 0; j < FC_GRP; ++j) {
                    const float4* ap = (const float4*)&al[(g8 * FC_GRP + j) * 68 + 16 * wv];
#pragma unroll
                    for (int i = 0; i < 4; ++i) {
                        float4 a = ap[i];
                        acc[4 * i + 0] = fmaf(a.x, wbuf[j], acc[4 * i + 0]);
                        acc[4 * i + 1] = fmaf(a.y, wbuf[j], acc[4 * i + 1]);
                        acc[4 * i + 2] = fmaf(a.z, wbuf[j], acc[4 * i + 2]);
                        acc[4 * i + 3] = fmaf(a.w, wbuf[j], acc[4 * i + 3]);
                    }
                }
            }
        } else {
            int kc0 = 0;
            for (; kc0 + FC_GRP <= kcur; kc0 += FC_GRP) {
                float wbuf[FC_GRP];
#pragma unroll
                for (int j = 0; j < FC_GRP; ++j)
                    wbuf[j] = wr[(size_t)(kc0 + j) * N];
#pragma unroll
                for (int j = 0; j < FC_GRP; ++j) {
                    const float4* ap = (const float4*)&al[(kc0 + j) * 68 + 16 * wv];
#pragma unroll
                    for (int i = 0; i < 4; ++i) {
                        float4 a = ap[i];
                        acc[4 * i + 0] = fmaf(a.x, wbuf[j], acc[4 * i + 0]);
                        acc[4 * i + 1] = fmaf(a.y, wbuf[j], acc[4 * i + 1]);
                        acc[4 * i + 2] = fmaf(a.z, wbuf[j], acc[4 * i + 2]);
                        acc[4 * i + 3] = fmaf(a.w, wbuf[j], acc[4 * i + 3]);
                    }
                }
            }
            for (; kc0 < kcur; ++kc0) {
                float wvv = wr[(size_t)kc0 * N];
                const float4* ap = (const float4*)&al[kc0 * 68 + 16 * wv];
#pragma unroll
                for (int i = 0; i < 4; ++i) {
                    float4 a = ap[i];
                    acc[4 * i + 0] = fmaf(a.x, wvv, acc[4 * i + 0]);
                    acc[4 * i + 1] = fmaf(a.y, wvv, acc[4 * i + 1]);
                    acc[4 * i + 2] = fmaf(a.z, wvv, acc[4 * i + 2]);
                    acc[4 * i + 3] = fmaf(a.w, wvv, acc[4 * i + 3]);
                }
            }
        }
    }

    if (n < N) {
        float* pr = out + n;
#pragma unroll
        for (int i = 0; i < 16; ++i)
            unsafeAtomicAdd(&pr[(size_t)(16 * wv + i) * N], acc[i]);
    }
}

extern "C" void kernel_launch(void* const* d_in, const int* in_sizes, int n_in,
                              void* d_out, int out_size, void* d_ws, size_t ws_size,
                              hipStream_t stream) {
    const float* x1  = (const float*)d_in[0];
    const float* x2  = (const float*)d_in[1];
    const float* wx1 = (const float*)d_in[2];
    const float* wh1 = (const float*)d_in[3];
    const float* bx1 = (const float*)d_in[4];
    const float* bh1 = (const float*)d_in[5];
    const float* wx2 = (const float*)d_in[6];
    const float* wh2 = (const float*)d_in[7];
    const float* bx2 = (const float*)d_in[8];
    const float* bh2 = (const float*)d_in[9];
    const float* fw2 = (const float*)d_in[10];
    const float* fb2 = (const float*)d_in[11];
    const float* fw3 = (const float*)d_in[12];
    const float* fb3 = (const float*)d_in[13];
    const float* fw4 = (const float*)d_in[14];
    const float* fb4 = (const float*)d_in[15];
    const float* fw5 = (const float*)d_in[16];
    const float* fb5 = (const float*)d_in[17];

    char* ws = (char*)d_ws;
    float* feat = (float*)ws;                                   // [64][7040]
    float* t1   = feat + (size_t)64 * 7040;                     // [64][3400]
    float* t2   = t1   + (size_t)64 * 3400;                     // [64][1000]
    float* t3   = t2   + (size_t)64 * 1000;                     // [64][500]
    float* o    = (float*)d_out;                                // [64][50]

    // bias pre-fill for all four FC outputs (316800 elems)
    fc_init<<<dim3(1238), dim3(256), 0, stream>>>(fb2, fb3, fb4, fb5, t1, t2, t3, o);

    lstm_kernel<<<dim3(220), dim3(256), 0, stream>>>(
        x1, x2, wx1, wh1, bx1, bh1, wx2, wh2, bx2, bh2, feat);

    // atomic split-K GEMMs (out pre-filled with bias)
    fc_gemm<<<dim3(54, 28), dim3(256), 0, stream>>>(feat, fw2, t1, 7040, 3400, 256);
    fc_gemm<<<dim3(16, 54), dim3(256), 0, stream>>>(t1, fw3, t2, 3400, 1000, 64);
    fc_gemm<<<dim3(8, 16), dim3(256), 0, stream>>>(t2, fw4, t3, 1000, 500, 64);
    fc_gemm<<<dim3(1, 16), dim3(256), 0, stream>>>(t3, fw5, o, 500, 50, 32);
}

// Round 9
// 572.419 us; speedup vs baseline: 1.1054x; 1.0020x over previous
//
#include <hip/hip_runtime.h>

// ---------------------------------------------------------------------------
// ConvLSTMNet round 16:
//  - lstm: exact R10 (best measured 317 us, 80 VGPR, 4-wave blocks).
//  - FC: MFMA fc_gemm. out = A@W via bf16 hi/lo split (3 products:
//    hi*hi + lo*hi + hi*lo), the same verified machinery as the lstm kernel.
//    A (64 x kchunk) staged in LDS pre-converted to bf16 hi/lo (pad 8 ->
//    2-way-free ds_read_b128); W converted in-flight (read exactly once
//    machine-wide). Wave = 16-col n-subtile, computes 4 m-tiles (acc 16 reg).
//    Atomic split-K into bias-pre-filled outputs (fc_init) kept.
//    Error ~1e-6 (fp32 MFMA accum; dropped lo*lo ~ 2^-18 rel).
// ---------------------------------------------------------------------------

#define T_STEPS 256
#define PIX 55
#define MT 16          // sequences per tile (MFMA N-dim)
#define TILES 110      // 1760 / 16
#define LOG2E 1.4426950408889634f
#define FCM_STAGE 128  // k per LDS stage in fc_gemm
#define FCM_PAD 8      // bf16 pad -> ds_read_b128 2-way (free) banks

typedef float f32x4 __attribute__((ext_vector_type(4)));
typedef __bf16 bf16x8 __attribute__((ext_vector_type(8)));
typedef __bf16 bf16x4 __attribute__((ext_vector_type(4)));

__global__ __launch_bounds__(256) void lstm_kernel(
    const float* __restrict__ x1, const float* __restrict__ x2,
    const float* __restrict__ wx1, const float* __restrict__ wh1,
    const float* __restrict__ bx1, const float* __restrict__ bh1,
    const float* __restrict__ wx2, const float* __restrict__ wh2,
    const float* __restrict__ bx2, const float* __restrict__ bh2,
    float* __restrict__ feat)   // [64][7040]: row sub*32+b, col (cell*64+u)*55+p
{
    int bid  = blockIdx.x;            // 0..439
    int tile = bid % TILES;
    int cc   = bid / TILES;           // 0..3
    int sub  = cc >> 1, cell = cc & 1;
    const float* x  = sub  ? x2  : x1;
    const float* wx = cell ? wx2 : wx1;
    const float* wh = cell ? wh2 : wh1;
    const float* bx = cell ? bx2 : bx1;
    const float* bh = cell ? bh2 : bh1;

    int tid  = threadIdx.x;
    int w    = tid >> 6;              // wave id = unit subtile (units 16w..16w+15)
    int l    = tid & 63;
    int quad = l >> 4;
    int c16  = l & 15;

    __shared__ float xl[MT * 514];                        // [seq][t*2+c], pad 514
    __shared__ __align__(16) __bf16 hb[2][2][MT][72];     // [buf][hi/lo][seq][u pad72]

    // ---- stage x for this block's 16 sequences (all 256 steps) ----
    {
        int seq0 = tile * MT;
        for (int i = 0; i < 32; ++i) {
            int idx = tid + 256 * i;          // m*512 + t*2 + c
            int m = idx >> 9;
            int tc = idx & 511;
            int t = tc >> 1, c = tc & 1;
            int seq = seq0 + m;
            int b = seq / PIX, p = seq % PIX;
            xl[m * 514 + tc] = x[((b * T_STEPS + t) * 2 + c) * PIX + p];
        }
    }
    // ---- zero h buffers ----
    {
        __bf16* hz = &hb[0][0][0][0];
        for (int i = tid; i < 2 * 2 * MT * 72; i += 256) hz[i] = (__bf16)0.0f;
    }

    // ---- W as A-operand fragments (hi+lo), per gate & K-slab ----
    bf16x8 Whi[4][2], Wlo[4][2];
    float btot[4][4], wxa[4][4], wxb[4][4];
#pragma unroll
    for (int g = 0; g < 4; ++g) {
        int col = 64 * g + 16 * w + c16;
#pragma unroll
        for (int r = 0; r < 4; ++r) {
            int u = 64 * g + 16 * w + 4 * quad + r;   // this thread's C-row units
            btot[g][r] = bx[u] + bh[u];
            wxa[g][r]  = wx[u];
            wxb[g][r]  = wx[256 + u];
        }
#pragma unroll
        for (int q = 0; q < 2; ++q) {
#pragma unroll
            for (int j = 0; j < 8; ++j) {
                int k = 32 * q + 8 * quad + j;
                float wv = wh[k * 256 + col];
                __bf16 hi = (__bf16)wv;
                Whi[g][q][j] = hi;
                Wlo[g][q][j] = (__bf16)(wv - (float)hi);
            }
        }
    }

    float cst[4]  = {0.f, 0.f, 0.f, 0.f};
    float hfin[4] = {0.f, 0.f, 0.f, 0.f};

    // xv for step 0 (xl is read-only after staging; prefetched pre-barrier
    // for every later step)
    __syncthreads();
    float2 xv = *(const float2*)&xl[c16 * 514 + (cell ? (T_STEPS - 1) : 0) * 2];

#pragma unroll 2
    for (int t = 0; t < T_STEPS; ++t) {
        int rb = t & 1, wb = rb ^ 1;

        bf16x8 Bh[2], Bl[2];
#pragma unroll
        for (int q = 0; q < 2; ++q) {
            Bh[q] = *(const bf16x8*)&hb[rb][0][c16][32 * q + 8 * quad];
            Bl[q] = *(const bf16x8*)&hb[rb][1][c16][32 * q + 8 * quad];
        }

        f32x4 acc[4];
#pragma unroll
        for (int g = 0; g < 4; ++g) {
#pragma unroll
            for (int r = 0; r < 4; ++r)
                acc[g][r] = fmaf(xv.y, wxb[g][r], fmaf(xv.x, wxa[g][r], btot[g][r]));
        }
        // product-major: 6 rounds x 4 gates -> 4-way dependent-chain ILP.
#pragma unroll
        for (int g = 0; g < 4; ++g)
            acc[g] = __builtin_amdgcn_mfma_f32_16x16x32_bf16(Whi[g][0], Bh[0], acc[g], 0, 0, 0);
#pragma unroll
        for (int g = 0; g < 4; ++g)
            acc[g] = __builtin_amdgcn_mfma_f32_16x16x32_bf16(Whi[g][1], Bh[1], acc[g], 0, 0, 0);
#pragma unroll
        for (int g = 0; g < 4; ++g)
            acc[g] = __builtin_amdgcn_mfma_f32_16x16x32_bf16(Wlo[g][0], Bh[0], acc[g], 0, 0, 0);
#pragma unroll
        for (int g = 0; g < 4; ++g)
            acc[g] = __builtin_amdgcn_mfma_f32_16x16x32_bf16(Wlo[g][1], Bh[1], acc[g], 0, 0, 0);
#pragma unroll
        for (int g = 0; g < 4; ++g)
            acc[g] = __builtin_amdgcn_mfma_f32_16x16x32_bf16(Whi[g][0], Bl[0], acc[g], 0, 0, 0);
#pragma unroll
        for (int g = 0; g < 4; ++g)
            acc[g] = __builtin_amdgcn_mfma_f32_16x16x32_bf16(Whi[g][1], Bl[1], acc[g], 0, 0, 0);

        // exp phase: 16 independent transcendentals, streamed
        float ei[4], ef[4], eo[4], eg[4];
#pragma unroll
        for (int r = 0; r < 4; ++r) {
            ei[r] = __builtin_amdgcn_exp2f(-LOG2E * acc[0][r]);
            ef[r] = __builtin_amdgcn_exp2f(-LOG2E * acc[1][r]);
            eo[r] = __builtin_amdgcn_exp2f(-LOG2E * acc[2][r]);
            eg[r] = __builtin_amdgcn_exp2f(-2.0f * LOG2E * acc[3][r]);
        }

        bf16x4 ph, pl;
#pragma unroll
        for (int r = 0; r < 4; ++r) {
            float sf  = __builtin_amdgcn_rcpf(1.0f + ef[r]);
            float itg = (1.0f - eg[r]) * __builtin_amdgcn_rcpf((1.0f + ei[r]) * (1.0f + eg[r]));
            float c   = fmaf(sf, cst[r], itg);
            cst[r] = c;
            float ec = __builtin_amdgcn_exp2f(-2.0f * LOG2E * c);
            float h  = (1.0f - ec) * __builtin_amdgcn_rcpf((1.0f + eo[r]) * (1.0f + ec));
            hfin[r] = h;
            __bf16 hi = (__bf16)h;
            ph[r] = hi;
            pl[r] = (__bf16)(h - (float)hi);
        }
        *(bf16x4*)&hb[wb][0][c16][16 * w + 4 * quad] = ph;
        *(bf16x4*)&hb[wb][1][c16][16 * w + 4 * quad] = pl;

        // prefetch next step's x contribution BEFORE the barrier (xl is
        // read-only; &255 keeps the dead last-iteration index in-bounds)
        {
            int txn = (cell ? (T_STEPS - 2 - t) : (t + 1)) & 255;
            xv = *(const float2*)&xl[c16 * 514 + txn * 2];
        }
        __syncthreads();
    }

    {
        int seq = tile * MT + c16;
        int b = seq / PIX, p = seq % PIX;
#pragma unroll
        for (int r = 0; r < 4; ++r) {
            int u = 16 * w + 4 * quad + r;
            feat[(size_t)(sub * 32 + b) * 7040 + (cell * 64 + u) * PIX + p] = hfin[r];
        }
    }
}

// ---------------------------------------------------------------------------
// fc_init: pre-fill all four FC outputs with their bias rows.
// Layout: t1[64][3400], t2[64][1000], t3[64][500], o[64][50].
// ---------------------------------------------------------------------------
__global__ __launch_bounds__(256) void fc_init(
    const float* __restrict__ b2, const float* __restrict__ b3,
    const float* __restrict__ b4, const float* __restrict__ b5,
    float* __restrict__ t1, float* __restrict__ t2,
    float* __restrict__ t3, float* __restrict__ o)
{
    int i = blockIdx.x * 256 + threadIdx.x;
    const int n1 = 64 * 3400, n2 = 64 * 1000, n3 = 64 * 500, n4 = 64 * 50;
    if (i < n1) { t1[i] = b2[i % 3400]; return; }
    i -= n1;
    if (i < n2) { t2[i] = b3[i % 1000]; return; }
    i -= n2;
    if (i < n3) { t3[i] = b4[i % 500]; return; }
    i -= n3;
    if (i < n4) { o[i] = b5[i % 50]; }
}

// ---------------------------------------------------------------------------
// FC v7 (MFMA, atomic split-K): out[64][N] += A[64][chunk] @ W[chunk][N].
// Block = 64 m x 64 n, 4 waves; wave wv owns n-subtile 16wv..16wv+15 and
// computes all 4 m-tiles (acc = 4 x f32x4). Per 32-k slab & wave:
//   A-frags (lane: m=c16+16mt, k=8*quad+e) as bf16 hi/lo from LDS (b128),
//   W B-frag (lane: n=c16, k=8*quad+e) loaded f32, cvt hi/lo in-flight,
//   3 products: Ahi*Whi + Alo*Whi + Ahi*Wlo (lo*lo dropped, ~2^-18 rel).
// A staged pre-converted (hi/lo bf16, pad 8 -> conflict-free b128 reads),
// zero-filled beyond kcur so partial slabs contribute exactly 0.
// Fragment mappings identical to the (verified) lstm kernel above.
// ---------------------------------------------------------------------------
__global__ __launch_bounds__(256) void fc_gemm(const float* __restrict__ A,
                                               const float* __restrict__ W,
                                               float* __restrict__ out,
                                               int K, int N, int kchunk) {
    __shared__ __align__(16) __bf16 alh[64][FCM_STAGE + FCM_PAD];
    __shared__ __align__(16) __bf16 all[64][FCM_STAGE + FCM_PAD];

    int tid  = threadIdx.x;
    int l    = tid & 63;
    int wv   = tid >> 6;          // wave = n-subtile
    int quad = l >> 4;
    int c16  = l & 15;

    int k0   = blockIdx.y * kchunk;
    int kend = min(K, k0 + kchunk);

    int n  = blockIdx.x * 64 + 16 * wv + c16;
    int nc = min(n, N - 1);               // clamped load col (stores guarded)

    f32x4 acc[4];
#pragma unroll
    for (int mt = 0; mt < 4; ++mt) acc[mt] = (f32x4){0.f, 0.f, 0.f, 0.f};

    for (int ks = k0; ks < kend; ks += FCM_STAGE) {
        int kcur = min(FCM_STAGE, kend - ks);
        __syncthreads();                  // protect LDS reuse
        // ---- stage A[0:64][ks:ks+128] as bf16 hi/lo, zero-filled ----
#pragma unroll
        for (int i = 0; i < 32; ++i) {
            int idx = tid + 256 * i;      // 8192 = 64 x 128
            int m = idx >> 7, kc = idx & 127;
            float v = (kc < kcur) ? A[(size_t)m * K + ks + kc] : 0.0f;
            __bf16 hi = (__bf16)v;
            alh[m][kc] = hi;
            all[m][kc] = (__bf16)(v - (float)hi);
        }
        __syncthreads();

        int nslab = (kcur + 31) >> 5;
        for (int s = 0; s < nslab; ++s) {
            // W B-frag: col = c16 (lane n), k = 32s + 8*quad + e
            bf16x8 wh, wl;
#pragma unroll
            for (int e = 0; e < 8; ++e) {
                int kr = ks + 32 * s + 8 * quad + e;
                float wval = W[(size_t)min(kr, K - 1) * N + nc];
                __bf16 hi = (__bf16)wval;
                wh[e] = hi;
                wl[e] = (__bf16)(wval - (float)hi);
            }
            // A frags: 4 m-tiles, hi+lo (b128 reads, 2-way-free banks)
            int ko = 32 * s + 8 * quad;
            bf16x8 ah[4], alo[4];
#pragma unroll
            for (int mt = 0; mt < 4; ++mt) {
                ah[mt]  = *(const bf16x8*)&alh[c16 + 16 * mt][ko];
                alo[mt] = *(const bf16x8*)&all[c16 + 16 * mt][ko];
            }
            // 12 MFMA: product-major, 4-way ILP
#pragma unroll
            for (int mt = 0; mt < 4; ++mt)
                acc[mt] = __builtin_amdgcn_mfma_f32_16x16x32_bf16(ah[mt], wh, acc[mt], 0, 0, 0);
#pragma unroll
            for (int mt = 0; mt < 4; ++mt)
                acc[mt] = __builtin_amdgcn_mfma_f32_16x16x32_bf16(alo[mt], wh, acc[mt], 0, 0, 0);
#pragma unroll
            for (int mt = 0; mt < 4; ++mt)
                acc[mt] = __builtin_amdgcn_mfma_f32_16x16x32_bf16(ah[mt], wl, acc[mt], 0, 0, 0);
        }
    }

    if (n < N) {
#pragma unroll
        for (int mt = 0; mt < 4; ++mt)
#pragma unroll
            for (int r = 0; r < 4; ++r)
                unsafeAtomicAdd(&out[(size_t)(16 * mt + 4 * quad + r) * N + n], acc[mt][r]);
    }
}

extern "C" void kernel_launch(void* const* d_in, const int* in_sizes, int n_in,
                              void* d_out, int out_size, void* d_ws, size_t ws_size,
                              hipStream_t stream) {
    const float* x1  = (const float*)d_in[0];
    const float* x2  = (const float*)d_in[1];
    const float* wx1 = (const float*)d_in[2];
    const float* wh1 = (const float*)d_in[3];
    const float* bx1 = (const float*)d_in[4];
    const float* bh1 = (const float*)d_in[5];
    const float* wx2 = (const float*)d_in[6];
    const float* wh2 = (const float*)d_in[7];
    const float* bx2 = (const float*)d_in[8];
    const float* bh2 = (const float*)d_in[9];
    const float* fw2 = (const float*)d_in[10];
    const float* fb2 = (const float*)d_in[11];
    const float* fw3 = (const float*)d_in[12];
    const float* fb3 = (const float*)d_in[13];
    const float* fw4 = (const float*)d_in[14];
    const float* fb4 = (const float*)d_in[15];
    const float* fw5 = (const float*)d_in[16];
    const float* fb5 = (const float*)d_in[17];

    char* ws = (char*)d_ws;
    float* feat = (float*)ws;                                   // [64][7040]
    float* t1   = feat + (size_t)64 * 7040;                     // [64][3400]
    float* t2   = t1   + (size_t)64 * 3400;                     // [64][1000]
    float* t3   = t2   + (size_t)64 * 1000;                     // [64][500]
    float* o    = (float*)d_out;                                // [64][50]

    // bias pre-fill for all four FC outputs (316800 elems)
    fc_init<<<dim3(1238), dim3(256), 0, stream>>>(fb2, fb3, fb4, fb5, t1, t2, t3, o);

    lstm_kernel<<<dim3(440), dim3(256), 0, stream>>>(
        x1, x2, wx1, wh1, bx1, bh1, wx2, wh2, bx2, bh2, feat);

    // MFMA atomic split-K GEMMs (out pre-filled with bias)
    fc_gemm<<<dim3(54, 11), dim3(256), 0, stream>>>(feat, fw2, t1, 7040, 3400, 640);
    fc_gemm<<<dim3(16, 27), dim3(256), 0, stream>>>(t1, fw3, t2, 3400, 1000, 128);
    fc_gemm<<<dim3(8, 8), dim3(256), 0, stream>>>(t2, fw4, t3, 1000, 500, 128);
    fc_gemm<<<dim3(1, 4), dim3(256), 0, stream>>>(t3, fw5, o, 500, 50, 128);
}

// Round 10
// 535.896 us; speedup vs baseline: 1.1807x; 1.0682x over previous
//
#include <hip/hip_runtime.h>

// ---------------------------------------------------------------------------
// ConvLSTMNet round 17 (= R10 best-known + 2 micro-wins):
//  - lstm: R10 structure (product-major MFMA interleave, xv prefetch, exp
//    hoist, unroll-2, 4-wave blocks) + PRESCALE FOLD: -LOG2E (i,f,o) and
//    -2*LOG2E (g) baked into wxa/wxb/btot and Whi/Wlo at build time, so MFMA
//    output IS the exp2 argument (deletes 16 v_mul/wave-step in the
//    issue-bound exp phase). Same op set -> absmax ~1e-8.
//  - fc_init folded into the lstm launch as 10 extra blocks (bid>=440):
//    bias prefill runs concurrently with lstm; one fewer serial launch.
//  - FC: exact R10 (233 us; proven optimum across 7 variants).
// ---------------------------------------------------------------------------

#define T_STEPS 256
#define PIX 55
#define MT 16          // sequences per tile (MFMA N-dim)
#define TILES 110      // 1760 / 16
#define LSTM_BLOCKS 440
#define INIT_BLOCKS 10
#define LOG2E 1.4426950408889634f
#define FC_SUB 128     // kc per LDS stage
#define FC_GRP 16      // W pipeline depth

typedef float f32x4 __attribute__((ext_vector_type(4)));
typedef __bf16 bf16x8 __attribute__((ext_vector_type(8)));
typedef __bf16 bf16x4 __attribute__((ext_vector_type(4)));

__global__ __launch_bounds__(256) void lstm_kernel(
    const float* __restrict__ x1, const float* __restrict__ x2,
    const float* __restrict__ wx1, const float* __restrict__ wh1,
    const float* __restrict__ bx1, const float* __restrict__ bh1,
    const float* __restrict__ wx2, const float* __restrict__ wh2,
    const float* __restrict__ bx2, const float* __restrict__ bh2,
    float* __restrict__ feat,   // [64][7040]: row sub*32+b, col (cell*64+u)*55+p
    const float* __restrict__ fb2, const float* __restrict__ fb3,
    const float* __restrict__ fb4, const float* __restrict__ fb5,
    float* __restrict__ t1, float* __restrict__ t2,
    float* __restrict__ t3, float* __restrict__ o)
{
    int bid  = blockIdx.x;            // 0..449
    int tid  = threadIdx.x;

    if (bid >= LSTM_BLOCKS) {
        // ---- bias prefill for the FC outputs (runs under the lstm) ----
        int base = (bid - LSTM_BLOCKS) * 256 + tid;      // 0..2559
        const int n1 = 64 * 3400, n2 = 64 * 1000, n3 = 64 * 500, n4 = 64 * 50;
        const int tot = n1 + n2 + n3 + n4;               // 316800
        for (int i = base; i < tot; i += 256 * INIT_BLOCKS) {
            int j = i;
            if (j < n1) { t1[j] = fb2[j % 3400]; continue; }
            j -= n1;
            if (j < n2) { t2[j] = fb3[j % 1000]; continue; }
            j -= n2;
            if (j < n3) { t3[j] = fb4[j % 500]; continue; }
            o[j - n3] = fb5[(j - n3) % 50];
        }
        return;
    }

    int tile = bid % TILES;
    int cc   = bid / TILES;           // 0..3
    int sub  = cc >> 1, cell = cc & 1;
    const float* x  = sub  ? x2  : x1;
    const float* wx = cell ? wx2 : wx1;
    const float* wh = cell ? wh2 : wh1;
    const float* bx = cell ? bx2 : bx1;
    const float* bh = cell ? bh2 : bh1;

    int w    = tid >> 6;              // wave id = unit subtile (units 16w..16w+15)
    int l    = tid & 63;
    int quad = l >> 4;
    int c16  = l & 15;

    __shared__ float xl[MT * 514];                        // [seq][t*2+c], pad 514
    __shared__ __align__(16) __bf16 hb[2][2][MT][72];     // [buf][hi/lo][seq][u pad72]

    // ---- stage x for this block's 16 sequences (all 256 steps) ----
    {
        int seq0 = tile * MT;
        for (int i = 0; i < 32; ++i) {
            int idx = tid + 256 * i;          // m*512 + t*2 + c
            int m = idx >> 9;
            int tc = idx & 511;
            int t = tc >> 1, c = tc & 1;
            int seq = seq0 + m;
            int b = seq / PIX, p = seq % PIX;
            xl[m * 514 + tc] = x[((b * T_STEPS + t) * 2 + c) * PIX + p];
        }
    }
    // ---- zero h buffers ----
    {
        __bf16* hz = &hb[0][0][0][0];
        for (int i = tid; i < 2 * 2 * MT * 72; i += 256) hz[i] = (__bf16)0.0f;
    }

    // ---- W as A-operand fragments (hi+lo), per gate & K-slab, PRESCALED ----
    // gate scale: i,f,o -> -LOG2E ; g -> -2*LOG2E. MFMA output is then the
    // exp2 argument directly (e^{-pre} or e^{-2 pre}).
    bf16x8 Whi[4][2], Wlo[4][2];
    float btot[4][4], wxa[4][4], wxb[4][4];
#pragma unroll
    for (int g = 0; g < 4; ++g) {
        float sg = (g == 3) ? (-2.0f * LOG2E) : (-LOG2E);
        int col = 64 * g + 16 * w + c16;
#pragma unroll
        for (int r = 0; r < 4; ++r) {
            int u = 64 * g + 16 * w + 4 * quad + r;   // this thread's C-row units
            btot[g][r] = sg * (bx[u] + bh[u]);
            wxa[g][r]  = sg * wx[u];
            wxb[g][r]  = sg * wx[256 + u];
        }
#pragma unroll
        for (int q = 0; q < 2; ++q) {
#pragma unroll
            for (int j = 0; j < 8; ++j) {
                int k = 32 * q + 8 * quad + j;
                float wv = sg * wh[k * 256 + col];
                __bf16 hi = (__bf16)wv;
                Whi[g][q][j] = hi;
                Wlo[g][q][j] = (__bf16)(wv - (float)hi);
            }
        }
    }

    float cst[4]  = {0.f, 0.f, 0.f, 0.f};
    float hfin[4] = {0.f, 0.f, 0.f, 0.f};

    // xv for step 0 (xl is read-only after staging; prefetched pre-barrier
    // for every later step)
    __syncthreads();
    float2 xv = *(const float2*)&xl[c16 * 514 + (cell ? (T_STEPS - 1) : 0) * 2];

#pragma unroll 2
    for (int t = 0; t < T_STEPS; ++t) {
        int rb = t & 1, wb = rb ^ 1;

        bf16x8 Bh[2], Bl[2];
#pragma unroll
        for (int q = 0; q < 2; ++q) {
            Bh[q] = *(const bf16x8*)&hb[rb][0][c16][32 * q + 8 * quad];
            Bl[q] = *(const bf16x8*)&hb[rb][1][c16][32 * q + 8 * quad];
        }

        f32x4 acc[4];
#pragma unroll
        for (int g = 0; g < 4; ++g) {
#pragma unroll
            for (int r = 0; r < 4; ++r)
                acc[g][r] = fmaf(xv.y, wxb[g][r], fmaf(xv.x, wxa[g][r], btot[g][r]));
        }
        // product-major: 6 rounds x 4 gates -> 4-way dependent-chain ILP.
#pragma unroll
        for (int g = 0; g < 4; ++g)
            acc[g] = __builtin_amdgcn_mfma_f32_16x16x32_bf16(Whi[g][0], Bh[0], acc[g], 0, 0, 0);
#pragma unroll
        for (int g = 0; g < 4; ++g)
            acc[g] = __builtin_amdgcn_mfma_f32_16x16x32_bf16(Whi[g][1], Bh[1], acc[g], 0, 0, 0);
#pragma unroll
        for (int g = 0; g < 4; ++g)
            acc[g] = __builtin_amdgcn_mfma_f32_16x16x32_bf16(Wlo[g][0], Bh[0], acc[g], 0, 0, 0);
#pragma unroll
        for (int g = 0; g < 4; ++g)
            acc[g] = __builtin_amdgcn_mfma_f32_16x16x32_bf16(Wlo[g][1], Bh[1], acc[g], 0, 0, 0);
#pragma unroll
        for (int g = 0; g < 4; ++g)
            acc[g] = __builtin_amdgcn_mfma_f32_16x16x32_bf16(Whi[g][0], Bl[0], acc[g], 0, 0, 0);
#pragma unroll
        for (int g = 0; g < 4; ++g)
            acc[g] = __builtin_amdgcn_mfma_f32_16x16x32_bf16(Whi[g][1], Bl[1], acc[g], 0, 0, 0);

        // exp phase: 16 independent transcendentals (acc IS the exp2 arg)
        float ei[4], ef[4], eo[4], eg[4];
#pragma unroll
        for (int r = 0; r < 4; ++r) {
            ei[r] = __builtin_amdgcn_exp2f(acc[0][r]);
            ef[r] = __builtin_amdgcn_exp2f(acc[1][r]);
            eo[r] = __builtin_amdgcn_exp2f(acc[2][r]);
            eg[r] = __builtin_amdgcn_exp2f(acc[3][r]);
        }

        bf16x4 ph, pl;
#pragma unroll
        for (int r = 0; r < 4; ++r) {
            float sf  = __builtin_amdgcn_rcpf(1.0f + ef[r]);
            float itg = (1.0f - eg[r]) * __builtin_amdgcn_rcpf((1.0f + ei[r]) * (1.0f + eg[r]));
            float c   = fmaf(sf, cst[r], itg);
            cst[r] = c;
            float ec = __builtin_amdgcn_exp2f(-2.0f * LOG2E * c);
            float h  = (1.0f - ec) * __builtin_amdgcn_rcpf((1.0f + eo[r]) * (1.0f + ec));
            hfin[r] = h;
            __bf16 hi = (__bf16)h;
            ph[r] = hi;
            pl[r] = (__bf16)(h - (float)hi);
        }
        *(bf16x4*)&hb[wb][0][c16][16 * w + 4 * quad] = ph;
        *(bf16x4*)&hb[wb][1][c16][16 * w + 4 * quad] = pl;

        // prefetch next step's x contribution BEFORE the barrier (xl is
        // read-only; &255 keeps the dead last-iteration index in-bounds)
        {
            int txn = (cell ? (T_STEPS - 2 - t) : (t + 1)) & 255;
            xv = *(const float2*)&xl[c16 * 514 + txn * 2];
        }
        __syncthreads();
    }

    {
        int seq = tile * MT + c16;
        int b = seq / PIX, p = seq % PIX;
#pragma unroll
        for (int r = 0; r < 4; ++r) {
            int u = 16 * w + 4 * quad + r;
            feat[(size_t)(sub * 32 + b) * 7040 + (cell * 64 + u) * PIX + p] = hfin[r];
        }
    }
}

// ---------------------------------------------------------------------------
// FC slim (R10, proven 233 us): out[64][N] += A[64][kchunk] @ W[kchunk][N].
// Block = 64 m x 64 n. Lane owns ONE n (acc[16] = 16 VGPR). Wave w -> rows
// 16w..16w+15 (broadcast b128 A reads). kcur==128 path: 8x16 static groups.
// Accumulation into bias-pre-initialized out via native f32 atomics.
// ---------------------------------------------------------------------------
__global__ __launch_bounds__(256) void fc_gemm(const float* __restrict__ A,
                                               const float* __restrict__ W,
                                               float* __restrict__ out,
                                               int K, int N, int kchunk) {
    __shared__ __align__(16) float al[FC_SUB * 68];   // [kc][m pad68]
    int tid = threadIdx.x;
    int l   = tid & 63;
    int wv  = tid >> 6;
    int k0   = blockIdx.y * kchunk;
    int kend = min(K, k0 + kchunk);

    int n  = blockIdx.x * 64 + l;
    int ne = min(n, N - 1);                // clamped load index (stores guarded)

    float acc[16];
#pragma unroll
    for (int i = 0; i < 16; ++i) acc[i] = 0.0f;

    for (int ks = k0; ks < kend; ks += FC_SUB) {
        int kcur = min(FC_SUB, kend - ks);
        __syncthreads();                   // protect al reuse
        // ---- stage A[0:64][ks:ks+kcur]: 32 independent coalesced loads ----
        if (kcur == FC_SUB) {
#pragma unroll
            for (int i = 0; i < 32; ++i) {
                int idx = tid + 256 * i;       // m = idx>>7, kc = idx&127
                int m = idx >> 7, kc = idx & 127;
                al[kc * 68 + m] = A[(size_t)m * K + ks + kc];
            }
        } else {
#pragma unroll
            for (int i = 0; i < 32; ++i) {
                int idx = tid + 256 * i;
                int m = idx >> 7, kc = idx & 127;
                if (kc < kcur) al[kc * 68 + m] = A[(size_t)m * K + ks + kc];
            }
        }
        __syncthreads();

        const float* wr = W + (size_t)ks * N + ne;
        if (kcur == FC_SUB) {
            // hot path: 8 static groups of 16, fully unrolled
#pragma unroll
            for (int g8 = 0; g8 < FC_SUB / FC_GRP; ++g8) {
                float wbuf[FC_GRP];
#pragma unroll
                for (int j = 0; j < FC_GRP; ++j)
                    wbuf[j] = wr[(size_t)(g8 * FC_GRP + j) * N];
#pragma unroll
                for (int j = 0; j < FC_GRP; ++j) {
                    const float4* ap = (const float4*)&al[(g8 * FC_GRP + j) * 68 + 16 * wv];
#pragma unroll
                    for (int i = 0; i < 4; ++i) {
                        float4 a = ap[i];
                        acc[4 * i + 0] = fmaf(a.x, wbuf[j], acc[4 * i + 0]);
                        acc[4 * i + 1] = fmaf(a.y, wbuf[j], acc[4 * i + 1]);
                        acc[4 * i + 2] = fmaf(a.z, wbuf[j], acc[4 * i + 2]);
                        acc[4 * i + 3] = fmaf(a.w, wbuf[j], acc[4 * i + 3]);
                    }
                }
            }
        } else {
            int kc0 = 0;
            for (; kc0 + FC_GRP <= kcur; kc0 += FC_GRP) {
                float wbuf[FC_GRP];
#pragma unroll
                for (int j = 0; j < FC_GRP; ++j)
                    wbuf[j] = wr[(size_t)(kc0 + j) * N];
#pragma unroll
                for (int j = 0; j < FC_GRP; ++j) {
                    const float4* ap = (const float4*)&al[(kc0 + j) * 68 + 16 * wv];
#pragma unroll
                    for (int i = 0; i < 4; ++i) {
                        float4 a = ap[i];
                        acc[4 * i + 0] = fmaf(a.x, wbuf[j], acc[4 * i + 0]);
                        acc[4 * i + 1] = fmaf(a.y, wbuf[j], acc[4 * i + 1]);
                        acc[4 * i + 2] = fmaf(a.z, wbuf[j], acc[4 * i + 2]);
                        acc[4 * i + 3] = fmaf(a.w, wbuf[j], acc[4 * i + 3]);
                    }
                }
            }
            for (; kc0 < kcur; ++kc0) {
                float wvv = wr[(size_t)kc0 * N];
                const float4* ap = (const float4*)&al[kc0 * 68 + 16 * wv];
#pragma unroll
                for (int i = 0; i < 4; ++i) {
                    float4 a = ap[i];
                    acc[4 * i + 0] = fmaf(a.x, wvv, acc[4 * i + 0]);
                    acc[4 * i + 1] = fmaf(a.y, wvv, acc[4 * i + 1]);
                    acc[4 * i + 2] = fmaf(a.z, wvv, acc[4 * i + 2]);
                    acc[4 * i + 3] = fmaf(a.w, wvv, acc[4 * i + 3]);
                }
            }
        }
    }

    if (n < N) {
        float* pr = out + n;
#pragma unroll
        for (int i = 0; i < 16; ++i)
            unsafeAtomicAdd(&pr[(size_t)(16 * wv + i) * N], acc[i]);
    }
}

extern "C" void kernel_launch(void* const* d_in, const int* in_sizes, int n_in,
                              void* d_out, int out_size, void* d_ws, size_t ws_size,
                              hipStream_t stream) {
    const float* x1  = (const float*)d_in[0];
    const float* x2  = (const float*)d_in[1];
    const float* wx1 = (const float*)d_in[2];
    const float* wh1 = (const float*)d_in[3];
    const float* bx1 = (const float*)d_in[4];
    const float* bh1 = (const float*)d_in[5];
    const float* wx2 = (const float*)d_in[6];
    const float* wh2 = (const float*)d_in[7];
    const float* bx2 = (const float*)d_in[8];
    const float* bh2 = (const float*)d_in[9];
    const float* fw2 = (const float*)d_in[10];
    const float* fb2 = (const float*)d_in[11];
    const float* fw3 = (const float*)d_in[12];
    const float* fb3 = (const float*)d_in[13];
    const float* fw4 = (const float*)d_in[14];
    const float* fb4 = (const float*)d_in[15];
    const float* fw5 = (const float*)d_in[16];
    const float* fb5 = (const float*)d_in[17];

    char* ws = (char*)d_ws;
    float* feat = (float*)ws;                                   // [64][7040]
    float* t1   = feat + (size_t)64 * 7040;                     // [64][3400]
    float* t2   = t1   + (size_t)64 * 3400;                     // [64][1000]
    float* t3   = t2   + (size_t)64 * 1000;                     // [64][500]
    float* o    = (float*)d_out;                                // [64][50]

    // lstm (440 blocks) + bias prefill (10 blocks) in one launch
    lstm_kernel<<<dim3(LSTM_BLOCKS + INIT_BLOCKS), dim3(256), 0, stream>>>(
        x1, x2, wx1, wh1, bx1, bh1, wx2, wh2, bx2, bh2, feat,
        fb2, fb3, fb4, fb5, t1, t2, t3, o);

    // atomic split-K GEMMs (out pre-filled with bias)
    fc_gemm<<<dim3(54, 28), dim3(256), 0, stream>>>(feat, fw2, t1, 7040, 3400, 256);
    fc_gemm<<<dim3(16, 54), dim3(256), 0, stream>>>(t1, fw3, t2, 3400, 1000, 64);
    fc_gemm<<<dim3(8, 16), dim3(256), 0, stream>>>(t2, fw4, t3, 1000, 500, 64);
    fc_gemm<<<dim3(1, 16), dim3(256), 0, stream>>>(t3, fw5, o, 500, 50, 32);
}